// Round 9
// baseline (545.031 us; speedup 1.0000x reference)
//
#include <hip/hip_runtime.h>
#include <hip/hip_bf16.h>
#include <hip/hip_fp16.h>
#include <math.h>

typedef unsigned int u32;
typedef unsigned short u16;

// f32 weight-blob offsets (in floats)
#define O_W1 0
#define O_b1 16384
#define O_W2 16512
#define O_b2 24704
#define O_W3 24768
#define O_b3 29056
#define O_P1 29123
#define O_pb1 31171
#define O_P2 31203
#define O_pb2 31235
#define W_TOTAL 31236

// dt codes: 0 = f32, 1 = bf16, 2 = f16
__device__ __forceinline__ float ldf(const void* p, long i, int dt) {
  if (dt == 1) { u32 v = ((const u16*)p)[i]; return __uint_as_float(v << 16); }
  if (dt == 2) { __half h = ((const __half*)p)[i]; return __half2float(h); }
  return ((const float*)p)[i];
}
__device__ __forceinline__ int ldei(const int* p, long i, int is64) {
  return is64 ? p[2 * i] : p[i];
}

// hdr: [0]=dt_feat [1]=dt_w [2]=ei is64 [3]=dt_ops
extern "C" __global__ void kd_detect(const u32* __restrict__ p,
                                     int* __restrict__ hdr, int slot)
{
  int lane = threadIdx.x;                 // 64 threads, 1 block
  u32 w0 = p[lane];
  u32 w1 = p[64 + lane];
  u16 h[4] = { (u16)(w0 & 0xffff), (u16)(w0 >> 16),
               (u16)(w1 & 0xffff), (u16)(w1 >> 16) };
  int cb = 0;
#pragma unroll
  for (int t = 0; t < 4; ++t) {
    int e8 = (h[t] >> 7) & 0xff;
    cb += (e8 >= 110 && e8 <= 140) ? 1 : 0;
  }
  int ch = 0;                              // f16 check on EVEN u16s only
#pragma unroll
  for (int t = 0; t < 4; t += 2) {
    int e5 = (h[t] >> 10) & 0x1f;
    ch += (e5 >= 5 && e5 <= 18) ? 1 : 0;
  }
  __shared__ int sb[64], sh[64];
  sb[lane] = cb; sh[lane] = ch;
  __syncthreads();
  if (lane == 0) {
    int CB = 0, CH = 0;
    for (int t = 0; t < 64; ++t) { CB += sb[t]; CH += sh[t]; }
    int dt;
    if (CB >= 200) dt = 1;
    else if (CH >= 100) dt = 2;
    else dt = 0;
    hdr[slot] = dt;
  }
}

extern "C" __global__ void ke_detect(const u32* __restrict__ p,
                                     int* __restrict__ hdr)
{
  int lane = threadIdx.x;
  unsigned long long m0 = __ballot(p[lane] == 0u);
  unsigned long long m1 = __ballot(p[64 + lane] == 0u);
  if (lane == 0) hdr[2] = (__popcll(m0) + __popcll(m1) >= 32) ? 1 : 0;
}

// ---------- KW: weights -> f32 blob ----------
extern "C" __global__ void __launch_bounds__(256)
kw_conv(const void* __restrict__ W1, const void* __restrict__ b1,
        const void* __restrict__ W2, const void* __restrict__ b2,
        const void* __restrict__ W3, const void* __restrict__ b3,
        const void* __restrict__ P1, const void* __restrict__ pb1,
        const void* __restrict__ P2, const void* __restrict__ pb2,
        const int* __restrict__ hdr, float* __restrict__ wf)
{
  int i = blockIdx.x * 256 + threadIdx.x;
  if (i >= W_TOTAL) return;
  const void* s; int o;
  if      (i < O_b1)  { s = W1;  o = i; }
  else if (i < O_W2)  { s = b1;  o = i - O_b1; }
  else if (i < O_b2)  { s = W2;  o = i - O_W2; }
  else if (i < O_W3)  { s = b2;  o = i - O_b2; }
  else if (i < O_b3)  { s = W3;  o = i - O_W3; }
  else if (i < O_P1)  { s = b3;  o = i - O_b3; }
  else if (i < O_pb1) { s = P1;  o = i - O_P1; }
  else if (i < O_P2)  { s = pb1; o = i - O_pb1; }
  else if (i < O_pb2) { s = P2;  o = i - O_P2; }
  else                { s = pb2; o = i - O_pb2; }
  wf[i] = ldf(s, o, hdr[1]);
}

// ---------- K0: degrees ----------
extern "C" __global__ void __launch_bounds__(256)
k0_deg(const int* __restrict__ ei, int* __restrict__ deg, int E,
       const int* __restrict__ hdr)
{
  int e = blockIdx.x * 256 + threadIdx.x;
  if (e >= E) return;
  int is64 = hdr[2];
  atomicAdd(deg + ldei(ei, e, is64), 1);
  atomicAdd(deg + ldei(ei, (long)E + e, is64), 1);
}

// ---------- K2: mask ----------
extern "C" __global__ void __launch_bounds__(256)
k2_mask(const void* __restrict__ opsv, const int* __restrict__ deg,
        const int* __restrict__ hdr, unsigned char* __restrict__ maskarr, int N)
{
  int i = blockIdx.x * 256 + threadIdx.x;
  if (i >= N) return;
  int dt = hdr[3];
  float x0 = ldf(opsv, (long)i * 4 + 0, dt);
  float x1 = ldf(opsv, (long)i * 4 + 1, dt);
  float x2 = ldf(opsv, (long)i * 4 + 2, dt);
  float x3 = ldf(opsv, (long)i * 4 + 3, dt);
  float m = fmaxf(fmaxf(x0, x1), fmaxf(x2, x3));
  double e0 = exp((double)(x0 - m));
  double e1 = exp((double)(x1 - m));
  double e2 = exp((double)(x2 - m));
  double e3 = exp((double)(x3 - m));
  double p0 = e0 / (((e0 + e1) + e2) + e3);
  maskarr[i] = (p0 > 0.5 && deg[i] > 0) ? 1 : 0;
}

// ---------- K1: feature scatter, one thread per (edge, feature) ----------
extern "C" __global__ void __launch_bounds__(256)
k1_feat(const int* __restrict__ ei, const void* __restrict__ featv,
        const unsigned char* __restrict__ maskarr, float* __restrict__ accf,
        int E, const int* __restrict__ hdr)
{
  long gid = (long)blockIdx.x * 256 + threadIdx.x;
  if (gid >= (long)E * 64) return;
  int e = (int)(gid >> 6);
  int f = (int)(gid & 63);
  int is64 = hdr[2];
  int s = ldei(ei, e, is64);
  int d = ldei(ei, (long)E + e, is64);
  int ms = maskarr[s], md = maskarr[d];
  if (!ms && !md) return;
  int dt = hdr[0];
  if (ms) {  // nsum[s] += feat[d][f]
    float v = ldf(featv, (long)d * 64 + f, dt);
    atomicAdd(accf + (long)s * 64 + f, v);
  }
  if (md) {  // nsum[d] += feat[s][f]
    float v = ldf(featv, (long)s * 64 + f, dt);
    atomicAdd(accf + (long)d * 64 + f, v);
  }
}

// ---------- K3: MLP, one 64-thread block per node (jax (fan_in,fan_out)) ----
extern "C" __global__ void __launch_bounds__(64)
k3_mlp(const void* __restrict__ featv, const float* __restrict__ accf,
       const int* __restrict__ deg, const unsigned char* __restrict__ maskarr,
       const float* __restrict__ wf, const int* __restrict__ hdr,
       float* __restrict__ out, int N)
{
  int node = blockIdx.x;
  if (node >= N) return;
  if (!maskarr[node]) return;            // output row stays zero
  int t = threadIdx.x;                   // 0..63
  int dt = hdr[0];
  __shared__ float ctx[128];
  __shared__ float h1[128];
  __shared__ float h2[64];
  __shared__ float gen[67];
  __shared__ float pp[32];
  __shared__ float prob;

  ctx[t]      = ldf(featv, (long)node * 64 + t, dt);
  ctx[64 + t] = accf[(long)node * 64 + t] / fmaxf((float)deg[node], 1.0f);
  __syncthreads();

  // L1: y_j = b1[j] + sum_k ctx[k]*W1[k*128+j], relu
  for (int rep = 0; rep < 2; ++rep) {
    int j = t + rep * 64;
    float a = wf[O_b1 + j];
    for (int k = 0; k < 128; ++k) a = fmaf(ctx[k], wf[O_W1 + k * 128 + j], a);
    h1[j] = fmaxf(a, 0.f);
  }
  __syncthreads();

  // L2
  {
    float a = wf[O_b2 + t];
    for (int k = 0; k < 128; ++k) a = fmaf(h1[k], wf[O_W2 + k * 64 + t], a);
    h2[t] = fmaxf(a, 0.f);
  }
  __syncthreads();

  // L3
  for (int j = t; j < 67; j += 64) {
    float a = wf[O_b3 + j];
    for (int k = 0; k < 64; ++k) a = fmaf(h2[k], wf[O_W3 + k * 67 + j], a);
    gen[j] = a;
  }
  __syncthreads();

  // L4: input gen[3..66]
  if (t < 32) {
    float a = wf[O_pb1 + t];
    for (int k = 0; k < 64; ++k) a = fmaf(gen[3 + k], wf[O_P1 + k * 32 + t], a);
    pp[t] = fmaxf(a, 0.f);
  }
  __syncthreads();

  // L5
  if (t == 0) {
    float z = wf[O_pb2];
    for (int k = 0; k < 32; ++k) z = fmaf(pp[k], wf[O_P2 + k], z);
    prob = 1.0f / (1.0f + expf(-z));
  }
  __syncthreads();

  for (int c = t; c < 68; c += 64) {
    float v = (c < 67) ? gen[c] : prob;
    out[(long)node * 68 + c] = v;        // f32 OUTPUT
  }
}

extern "C" void kernel_launch(void* const* d_in, const int* in_sizes, int n_in,
                              void* d_out, int out_size, void* d_ws, size_t ws_size,
                              hipStream_t stream) {
  // ---- identify tensors by element count (fallback: documented order) ----
  int iF = 0, iO = 1, iE = 2;
  int iW1 = 3, ib1 = 4, iW2 = 5, ib2 = 6, iW3 = 7, ib3 = 8;
  int iP1 = 9, ipb1 = 10, iP2 = 11, ipb2 = 12;
  {
    int bigs[4]; int nb = 0;
    for (int i = 0; i < n_in && nb < 4; ++i)
      if (in_sizes[i] > 100000) bigs[nb++] = i;
    if (nb == 3) {
      int a = bigs[0], b = bigs[1], c = bigs[2];
      int mx = a, mn = a;
      if (in_sizes[b] > in_sizes[mx]) mx = b;
      if (in_sizes[c] > in_sizes[mx]) mx = c;
      if (in_sizes[b] < in_sizes[mn]) mn = b;
      if (in_sizes[c] < in_sizes[mn]) mn = c;
      iF = mx; iO = mn; iE = a + b + c - mx - mn;
      int t32[2]; int n32 = 0;
      int jW1=-1, jb1=-1, jW2=-1, jb2=-1, jW3=-1, jb3=-1, jP1=-1, jpb2=-1;
      for (int i = 0; i < n_in; ++i) {
        if (i == iF || i == iO || i == iE) continue;
        switch (in_sizes[i]) {
          case 16384: jW1 = i; break;
          case 128:   jb1 = i; break;
          case 8192:  jW2 = i; break;
          case 64:    jb2 = i; break;
          case 4288:  jW3 = i; break;
          case 67:    jb3 = i; break;
          case 2048:  jP1 = i; break;
          case 1:     jpb2 = i; break;
          case 32:    if (n32 < 2) t32[n32++] = i; break;
          default: break;
        }
      }
      if (jW1 >= 0 && jb1 >= 0 && jW2 >= 0 && jb2 >= 0 && jW3 >= 0 &&
          jb3 >= 0 && jP1 >= 0 && jpb2 >= 0 && n32 == 2) {
        iW1 = jW1; ib1 = jb1; iW2 = jW2; ib2 = jb2; iW3 = jW3; ib3 = jb3;
        iP1 = jP1; ipb2 = jpb2;
        if (t32[1] == t32[0] + 1) { ipb1 = t32[0]; iP2 = t32[1]; }
        else                      { iP2 = t32[0]; ipb1 = t32[1]; }
      }
    }
  }
  int N = (out_size % 68 == 0) ? (out_size / 68) : (in_sizes[iF] / 64);
  const int E = in_sizes[iE] / 2;
  const void* feat = d_in[iF];
  const void* ops  = d_in[iO];
  const int* ei    = (const int*)d_in[iE];

  // workspace: hdr | wf | deg | maskarr | accf(N*64 f32)
  char* ws = (char*)d_ws;
  int* hdr = (int*)ws;
  size_t off = 256;
  float* wf = (float*)(ws + off);
  off += ((size_t)W_TOTAL * 4 + 255) & ~(size_t)255;
  int* deg = (int*)(ws + off);
  off += ((size_t)N * 4 + 255) & ~(size_t)255;
  unsigned char* maskarr = (unsigned char*)(ws + off);
  off += ((size_t)N + 255) & ~(size_t)255;
  float* accf = (float*)(ws + off);

  hipMemsetAsync(hdr, 0, 256, stream);
  hipMemsetAsync(deg, 0, (size_t)N * 4, stream);
  hipMemsetAsync(accf, 0, (size_t)N * 64 * 4, stream);
  hipMemsetAsync(d_out, 0, (size_t)out_size * 4, stream);   // f32 output!

  kd_detect<<<1, 64, 0, stream>>>((const u32*)feat, hdr, 0);
  kd_detect<<<1, 64, 0, stream>>>((const u32*)d_in[iW1], hdr, 1);
  kd_detect<<<1, 64, 0, stream>>>((const u32*)ops, hdr, 3);
  ke_detect<<<1, 64, 0, stream>>>((const u32*)ei, hdr);

  kw_conv<<<(W_TOTAL + 255) / 256, 256, 0, stream>>>(
      d_in[iW1], d_in[ib1], d_in[iW2], d_in[ib2], d_in[iW3], d_in[ib3],
      d_in[iP1], d_in[ipb1], d_in[iP2], d_in[ipb2], hdr, wf);
  k0_deg<<<(E + 255) / 256, 256, 0, stream>>>(ei, deg, E, hdr);
  k2_mask<<<(N + 255) / 256, 256, 0, stream>>>(ops, deg, hdr, maskarr, N);
  {
    long nthr = (long)E * 64;
    int blocks = (int)((nthr + 255) / 256);
    k1_feat<<<blocks, 256, 0, stream>>>(ei, feat, maskarr, accf, E, hdr);
  }
  k3_mlp<<<N, 64, 0, stream>>>(feat, accf, deg, maskarr, wf, hdr,
                               (float*)d_out, N);
}

// Round 10
// 387.757 us; speedup vs baseline: 1.4056x; 1.4056x over previous
//
#include <hip/hip_runtime.h>
#include <hip/hip_bf16.h>
#include <hip/hip_fp16.h>
#include <math.h>

typedef unsigned int u32;
typedef unsigned short u16;

// f32 weight-blob offsets (in floats)
#define O_W1 0
#define O_b1 16384
#define O_W2 16512
#define O_b2 24704
#define O_W3 24768
#define O_b3 29056
#define O_P1 29123
#define O_pb1 31171
#define O_P2 31203
#define O_pb2 31235
#define W_TOTAL 31236

// dt codes: 0 = f32, 1 = bf16, 2 = f16
__device__ __forceinline__ float ldf(const void* p, long i, int dt) {
  if (dt == 1) { u32 v = ((const u16*)p)[i]; return __uint_as_float(v << 16); }
  if (dt == 2) { __half h = ((const __half*)p)[i]; return __half2float(h); }
  return ((const float*)p)[i];
}
__device__ __forceinline__ int ldei(const int* p, long i, int is64) {
  return is64 ? p[2 * i] : p[i];
}

// hdr: [0]=dt_feat [1]=dt_w [2]=ei is64 [3]=dt_ops [4]=masked count [5]=adj total
extern "C" __global__ void kd_detect(const u32* __restrict__ p,
                                     int* __restrict__ hdr, int slot)
{
  int lane = threadIdx.x;                 // 64 threads, 1 block
  u32 w0 = p[lane];
  u32 w1 = p[64 + lane];
  u16 h[4] = { (u16)(w0 & 0xffff), (u16)(w0 >> 16),
               (u16)(w1 & 0xffff), (u16)(w1 >> 16) };
  int cb = 0;
#pragma unroll
  for (int t = 0; t < 4; ++t) {
    int e8 = (h[t] >> 7) & 0xff;
    cb += (e8 >= 110 && e8 <= 140) ? 1 : 0;
  }
  int ch = 0;                              // f16 check on EVEN u16s only
#pragma unroll
  for (int t = 0; t < 4; t += 2) {
    int e5 = (h[t] >> 10) & 0x1f;
    ch += (e5 >= 5 && e5 <= 18) ? 1 : 0;
  }
  __shared__ int sb[64], sh[64];
  sb[lane] = cb; sh[lane] = ch;
  __syncthreads();
  if (lane == 0) {
    int CB = 0, CH = 0;
    for (int t = 0; t < 64; ++t) { CB += sb[t]; CH += sh[t]; }
    int dt;
    if (CB >= 200) dt = 1;
    else if (CH >= 100) dt = 2;
    else dt = 0;
    hdr[slot] = dt;
  }
}

extern "C" __global__ void ke_detect(const u32* __restrict__ p,
                                     int* __restrict__ hdr)
{
  int lane = threadIdx.x;
  unsigned long long m0 = __ballot(p[lane] == 0u);
  unsigned long long m1 = __ballot(p[64 + lane] == 0u);
  if (lane == 0) hdr[2] = (__popcll(m0) + __popcll(m1) >= 32) ? 1 : 0;
}

// ---------- KW: weights -> f32 blob ----------
extern "C" __global__ void __launch_bounds__(256)
kw_conv(const void* __restrict__ W1, const void* __restrict__ b1,
        const void* __restrict__ W2, const void* __restrict__ b2,
        const void* __restrict__ W3, const void* __restrict__ b3,
        const void* __restrict__ P1, const void* __restrict__ pb1,
        const void* __restrict__ P2, const void* __restrict__ pb2,
        const int* __restrict__ hdr, float* __restrict__ wf)
{
  int i = blockIdx.x * 256 + threadIdx.x;
  if (i >= W_TOTAL) return;
  const void* s; int o;
  if      (i < O_b1)  { s = W1;  o = i; }
  else if (i < O_W2)  { s = b1;  o = i - O_b1; }
  else if (i < O_b2)  { s = W2;  o = i - O_W2; }
  else if (i < O_W3)  { s = b2;  o = i - O_b2; }
  else if (i < O_b3)  { s = W3;  o = i - O_W3; }
  else if (i < O_P1)  { s = b3;  o = i - O_b3; }
  else if (i < O_pb1) { s = P1;  o = i - O_P1; }
  else if (i < O_P2)  { s = pb1; o = i - O_pb1; }
  else if (i < O_pb2) { s = P2;  o = i - O_P2; }
  else                { s = pb2; o = i - O_pb2; }
  wf[i] = ldf(s, o, hdr[1]);
}

// ---------- K0: degrees ----------
extern "C" __global__ void __launch_bounds__(256)
k0_deg(const int* __restrict__ ei, int* __restrict__ deg, int E,
       const int* __restrict__ hdr)
{
  int e = blockIdx.x * 256 + threadIdx.x;
  if (e >= E) return;
  int is64 = hdr[2];
  atomicAdd(deg + ldei(ei, e, is64), 1);
  atomicAdd(deg + ldei(ei, (long)E + e, is64), 1);
}

// ---------- K2: mask + compact + adjacency allocation ----------
// nodeoff[i] = start of node i's adjacency region, or -1 if unmasked
extern "C" __global__ void __launch_bounds__(256)
k2_mask(const void* __restrict__ opsv, const int* __restrict__ deg,
        int* __restrict__ hdr, int* __restrict__ nodeoff,
        int* __restrict__ nlist, int N)
{
  int i = blockIdx.x * 256 + threadIdx.x;
  if (i >= N) return;
  int dt = hdr[3];
  float x0 = ldf(opsv, (long)i * 4 + 0, dt);
  float x1 = ldf(opsv, (long)i * 4 + 1, dt);
  float x2 = ldf(opsv, (long)i * 4 + 2, dt);
  float x3 = ldf(opsv, (long)i * 4 + 3, dt);
  float m = fmaxf(fmaxf(x0, x1), fmaxf(x2, x3));
  double e0 = exp((double)(x0 - m));
  double e1 = exp((double)(x1 - m));
  double e2 = exp((double)(x2 - m));
  double e3 = exp((double)(x3 - m));
  double p0 = e0 / (((e0 + e1) + e2) + e3);
  int dg = deg[i];
  if (p0 > 0.5 && dg > 0) {
    int pos = atomicAdd(hdr + 4, 1);
    nlist[pos] = i;
    nodeoff[i] = atomicAdd(hdr + 5, dg);
  } else {
    nodeoff[i] = -1;
  }
}

// ---------- K1: fill adjacency lists of masked nodes ----------
extern "C" __global__ void __launch_bounds__(256)
k1_fill(const int* __restrict__ ei, const int* __restrict__ nodeoff,
        int* __restrict__ fillcnt, int* __restrict__ adj, int E,
        const int* __restrict__ hdr)
{
  int e = blockIdx.x * 256 + threadIdx.x;
  if (e >= E) return;
  int is64 = hdr[2];
  int s = ldei(ei, e, is64);
  int d = ldei(ei, (long)E + e, is64);
  int os = nodeoff[s];
  int od = nodeoff[d];
  if (os >= 0) { int p = atomicAdd(fillcnt + s, 1); adj[os + p] = d; }
  if (od >= 0) { int p = atomicAdd(fillcnt + d, 1); adj[od + p] = s; }
}

// ---------- K3: gather + MLP, one 64-thread block per masked node ----------
extern "C" __global__ void __launch_bounds__(64)
k3_mlp(const void* __restrict__ featv, const int* __restrict__ deg,
       const int* __restrict__ nodeoff, const int* __restrict__ nlist,
       const int* __restrict__ adj, const float* __restrict__ wf,
       const int* __restrict__ hdr, float* __restrict__ out, int N)
{
  int b = blockIdx.x;
  if (b >= hdr[4]) return;               // beyond masked count
  int node = nlist[b];
  int t = threadIdx.x;                   // 0..63 = feature lane
  int dt = hdr[0];
  __shared__ float ctx[128];
  __shared__ float h1[128];
  __shared__ float h2[64];
  __shared__ float gen[67];
  __shared__ float pp[32];
  __shared__ float prob;

  // gather neighbor mean (coalesced 256B row loads, 4-way unrolled)
  int off = nodeoff[node];
  int dg = deg[node];
  float acc = 0.f;
  int j = 0;
  for (; j + 4 <= dg; j += 4) {
    int n0 = adj[off + j + 0];
    int n1 = adj[off + j + 1];
    int n2 = adj[off + j + 2];
    int n3 = adj[off + j + 3];
    float v0 = ldf(featv, (long)n0 * 64 + t, dt);
    float v1 = ldf(featv, (long)n1 * 64 + t, dt);
    float v2 = ldf(featv, (long)n2 * 64 + t, dt);
    float v3 = ldf(featv, (long)n3 * 64 + t, dt);
    acc += ((v0 + v1) + (v2 + v3));
  }
  for (; j < dg; ++j) {
    int nb = adj[off + j];
    acc += ldf(featv, (long)nb * 64 + t, dt);
  }
  ctx[t]      = ldf(featv, (long)node * 64 + t, dt);
  ctx[64 + t] = acc / (float)dg;         // dg > 0 guaranteed by mask
  __syncthreads();

  // L1: y_j = b1[j] + sum_k ctx[k]*W1[k*128+j], relu
  for (int rep = 0; rep < 2; ++rep) {
    int jj = t + rep * 64;
    float a = wf[O_b1 + jj];
    for (int k = 0; k < 128; ++k) a = fmaf(ctx[k], wf[O_W1 + k * 128 + jj], a);
    h1[jj] = fmaxf(a, 0.f);
  }
  __syncthreads();

  // L2
  {
    float a = wf[O_b2 + t];
    for (int k = 0; k < 128; ++k) a = fmaf(h1[k], wf[O_W2 + k * 64 + t], a);
    h2[t] = fmaxf(a, 0.f);
  }
  __syncthreads();

  // L3
  for (int jj = t; jj < 67; jj += 64) {
    float a = wf[O_b3 + jj];
    for (int k = 0; k < 64; ++k) a = fmaf(h2[k], wf[O_W3 + k * 67 + jj], a);
    gen[jj] = a;
  }
  __syncthreads();

  // L4: input gen[3..66]
  if (t < 32) {
    float a = wf[O_pb1 + t];
    for (int k = 0; k < 64; ++k) a = fmaf(gen[3 + k], wf[O_P1 + k * 32 + t], a);
    pp[t] = fmaxf(a, 0.f);
  }
  __syncthreads();

  // L5
  if (t == 0) {
    float z = wf[O_pb2];
    for (int k = 0; k < 32; ++k) z = fmaf(pp[k], wf[O_P2 + k], z);
    prob = 1.0f / (1.0f + expf(-z));
  }
  __syncthreads();

  for (int c = t; c < 68; c += 64) {
    float v = (c < 67) ? gen[c] : prob;
    out[(long)node * 68 + c] = v;
  }
}

extern "C" void kernel_launch(void* const* d_in, const int* in_sizes, int n_in,
                              void* d_out, int out_size, void* d_ws, size_t ws_size,
                              hipStream_t stream) {
  // ---- identify tensors by element count (fallback: documented order) ----
  int iF = 0, iO = 1, iE = 2;
  int iW1 = 3, ib1 = 4, iW2 = 5, ib2 = 6, iW3 = 7, ib3 = 8;
  int iP1 = 9, ipb1 = 10, iP2 = 11, ipb2 = 12;
  {
    int bigs[4]; int nb = 0;
    for (int i = 0; i < n_in && nb < 4; ++i)
      if (in_sizes[i] > 100000) bigs[nb++] = i;
    if (nb == 3) {
      int a = bigs[0], b = bigs[1], c = bigs[2];
      int mx = a, mn = a;
      if (in_sizes[b] > in_sizes[mx]) mx = b;
      if (in_sizes[c] > in_sizes[mx]) mx = c;
      if (in_sizes[b] < in_sizes[mn]) mn = b;
      if (in_sizes[c] < in_sizes[mn]) mn = c;
      iF = mx; iO = mn; iE = a + b + c - mx - mn;
      int t32[2]; int n32 = 0;
      int jW1=-1, jb1=-1, jW2=-1, jb2=-1, jW3=-1, jb3=-1, jP1=-1, jpb2=-1;
      for (int i = 0; i < n_in; ++i) {
        if (i == iF || i == iO || i == iE) continue;
        switch (in_sizes[i]) {
          case 16384: jW1 = i; break;
          case 128:   jb1 = i; break;
          case 8192:  jW2 = i; break;
          case 64:    jb2 = i; break;
          case 4288:  jW3 = i; break;
          case 67:    jb3 = i; break;
          case 2048:  jP1 = i; break;
          case 1:     jpb2 = i; break;
          case 32:    if (n32 < 2) t32[n32++] = i; break;
          default: break;
        }
      }
      if (jW1 >= 0 && jb1 >= 0 && jW2 >= 0 && jb2 >= 0 && jW3 >= 0 &&
          jb3 >= 0 && jP1 >= 0 && jpb2 >= 0 && n32 == 2) {
        iW1 = jW1; ib1 = jb1; iW2 = jW2; ib2 = jb2; iW3 = jW3; ib3 = jb3;
        iP1 = jP1; ipb2 = jpb2;
        if (t32[1] == t32[0] + 1) { ipb1 = t32[0]; iP2 = t32[1]; }
        else                      { iP2 = t32[0]; ipb1 = t32[1]; }
      }
    }
  }
  int N = (out_size % 68 == 0) ? (out_size / 68) : (in_sizes[iF] / 64);
  const int E = in_sizes[iE] / 2;
  const void* feat = d_in[iF];
  const void* ops  = d_in[iO];
  const int* ei    = (const int*)d_in[iE];

  // workspace: hdr | wf | deg | nodeoff | fillcnt | nlist | adj(2E ints)
  char* ws = (char*)d_ws;
  int* hdr = (int*)ws;
  size_t off = 256;
  float* wf = (float*)(ws + off);
  off += ((size_t)W_TOTAL * 4 + 255) & ~(size_t)255;
  int* deg = (int*)(ws + off);
  off += ((size_t)N * 4 + 255) & ~(size_t)255;
  int* nodeoff = (int*)(ws + off);
  off += ((size_t)N * 4 + 255) & ~(size_t)255;
  int* fillcnt = (int*)(ws + off);
  off += ((size_t)N * 4 + 255) & ~(size_t)255;
  int* nlist = (int*)(ws + off);
  off += ((size_t)N * 4 + 255) & ~(size_t)255;
  int* adj = (int*)(ws + off);

  hipMemsetAsync(hdr, 0, 256, stream);
  hipMemsetAsync(deg, 0, (size_t)N * 4, stream);
  hipMemsetAsync(fillcnt, 0, (size_t)N * 4, stream);
  hipMemsetAsync(d_out, 0, (size_t)out_size * 4, stream);

  kd_detect<<<1, 64, 0, stream>>>((const u32*)feat, hdr, 0);
  kd_detect<<<1, 64, 0, stream>>>((const u32*)d_in[iW1], hdr, 1);
  kd_detect<<<1, 64, 0, stream>>>((const u32*)ops, hdr, 3);
  ke_detect<<<1, 64, 0, stream>>>((const u32*)ei, hdr);

  kw_conv<<<(W_TOTAL + 255) / 256, 256, 0, stream>>>(
      d_in[iW1], d_in[ib1], d_in[iW2], d_in[ib2], d_in[iW3], d_in[ib3],
      d_in[iP1], d_in[ipb1], d_in[iP2], d_in[ipb2], hdr, wf);
  k0_deg<<<(E + 255) / 256, 256, 0, stream>>>(ei, deg, E, hdr);
  k2_mask<<<(N + 255) / 256, 256, 0, stream>>>(ops, deg, hdr, nodeoff, nlist, N);
  k1_fill<<<(E + 255) / 256, 256, 0, stream>>>(ei, nodeoff, fillcnt, adj, E, hdr);
  k3_mlp<<<N, 64, 0, stream>>>(feat, deg, nodeoff, nlist, adj, wf, hdr,
                               (float*)d_out, N);
}

// Round 11
// 340.153 us; speedup vs baseline: 1.6023x; 1.1399x over previous
//
#include <hip/hip_runtime.h>
#include <hip/hip_bf16.h>
#include <hip/hip_fp16.h>
#include <math.h>

typedef unsigned int u32;
typedef unsigned short u16;

// f32 weight-blob offsets (in floats)
#define O_W1 0
#define O_b1 16384
#define O_W2 16512
#define O_b2 24704
#define O_W3 24768
#define O_b3 29056
#define O_P1 29123
#define O_pb1 31171
#define O_P2 31203
#define O_pb2 31235
#define W_TOTAL 31236

// dt codes: 0 = f32, 1 = bf16, 2 = f16
__device__ __forceinline__ float ldf(const void* p, long i, int dt) {
  if (dt == 1) { u32 v = ((const u16*)p)[i]; return __uint_as_float(v << 16); }
  if (dt == 2) { __half h = ((const __half*)p)[i]; return __half2float(h); }
  return ((const float*)p)[i];
}
__device__ __forceinline__ int ldei(const int* p, long i, int is64) {
  return is64 ? p[2 * i] : p[i];
}

// hdr: [0]=dt_feat [1]=dt_w [2]=ei is64 [3]=dt_ops [4]=masked count [5]=adj total
extern "C" __global__ void kd_detect(const u32* __restrict__ p,
                                     int* __restrict__ hdr, int slot)
{
  int lane = threadIdx.x;                 // 64 threads, 1 block
  u32 w0 = p[lane];
  u32 w1 = p[64 + lane];
  u16 h[4] = { (u16)(w0 & 0xffff), (u16)(w0 >> 16),
               (u16)(w1 & 0xffff), (u16)(w1 >> 16) };
  int cb = 0;
#pragma unroll
  for (int t = 0; t < 4; ++t) {
    int e8 = (h[t] >> 7) & 0xff;
    cb += (e8 >= 110 && e8 <= 140) ? 1 : 0;
  }
  int ch = 0;                              // f16 check on EVEN u16s only
#pragma unroll
  for (int t = 0; t < 4; t += 2) {
    int e5 = (h[t] >> 10) & 0x1f;
    ch += (e5 >= 5 && e5 <= 18) ? 1 : 0;
  }
  __shared__ int sb[64], sh[64];
  sb[lane] = cb; sh[lane] = ch;
  __syncthreads();
  if (lane == 0) {
    int CB = 0, CH = 0;
    for (int t = 0; t < 64; ++t) { CB += sb[t]; CH += sh[t]; }
    int dt;
    if (CB >= 200) dt = 1;
    else if (CH >= 100) dt = 2;
    else dt = 0;
    hdr[slot] = dt;
  }
}

extern "C" __global__ void ke_detect(const u32* __restrict__ p,
                                     int* __restrict__ hdr)
{
  int lane = threadIdx.x;
  unsigned long long m0 = __ballot(p[lane] == 0u);
  unsigned long long m1 = __ballot(p[64 + lane] == 0u);
  if (lane == 0) hdr[2] = (__popcll(m0) + __popcll(m1) >= 32) ? 1 : 0;
}

// ---------- KW: weights -> f32 blob ----------
extern "C" __global__ void __launch_bounds__(256)
kw_conv(const void* __restrict__ W1, const void* __restrict__ b1,
        const void* __restrict__ W2, const void* __restrict__ b2,
        const void* __restrict__ W3, const void* __restrict__ b3,
        const void* __restrict__ P1, const void* __restrict__ pb1,
        const void* __restrict__ P2, const void* __restrict__ pb2,
        const int* __restrict__ hdr, float* __restrict__ wf)
{
  int i = blockIdx.x * 256 + threadIdx.x;
  if (i >= W_TOTAL) return;
  const void* s; int o;
  if      (i < O_b1)  { s = W1;  o = i; }
  else if (i < O_W2)  { s = b1;  o = i - O_b1; }
  else if (i < O_b2)  { s = W2;  o = i - O_W2; }
  else if (i < O_W3)  { s = b2;  o = i - O_b2; }
  else if (i < O_b3)  { s = W3;  o = i - O_W3; }
  else if (i < O_P1)  { s = b3;  o = i - O_b3; }
  else if (i < O_pb1) { s = P1;  o = i - O_P1; }
  else if (i < O_P2)  { s = pb1; o = i - O_pb1; }
  else if (i < O_pb2) { s = P2;  o = i - O_P2; }
  else                { s = pb2; o = i - O_pb2; }
  wf[i] = ldf(s, o, hdr[1]);
}

// ---------- K2a: candidate flags (p0 > 0.5), no atomics ----------
extern "C" __global__ void __launch_bounds__(256)
k2a_cand(const void* __restrict__ opsv, const int* __restrict__ hdr,
         unsigned char* __restrict__ cand, int N)
{
  int i = blockIdx.x * 256 + threadIdx.x;
  if (i >= N) return;
  int dt = hdr[3];
  float x0 = ldf(opsv, (long)i * 4 + 0, dt);
  float x1 = ldf(opsv, (long)i * 4 + 1, dt);
  float x2 = ldf(opsv, (long)i * 4 + 2, dt);
  float x3 = ldf(opsv, (long)i * 4 + 3, dt);
  float m = fmaxf(fmaxf(x0, x1), fmaxf(x2, x3));
  double e0 = exp((double)(x0 - m));
  double e1 = exp((double)(x1 - m));
  double e2 = exp((double)(x2 - m));
  double e3 = exp((double)(x3 - m));
  double p0 = e0 / (((e0 + e1) + e2) + e3);
  cand[i] = (p0 > 0.5) ? 1 : 0;
}

// ---------- K1a: count degrees ONLY for candidate endpoints ----------
extern "C" __global__ void __launch_bounds__(256)
k1a_cnt(const int* __restrict__ ei, const unsigned char* __restrict__ cand,
        int* __restrict__ cnt, int E, const int* __restrict__ hdr)
{
  int e = blockIdx.x * 256 + threadIdx.x;
  if (e >= E) return;
  int is64 = hdr[2];
  int s = ldei(ei, e, is64);
  int d = ldei(ei, (long)E + e, is64);
  if (cand[s]) atomicAdd(cnt + s, 1);
  if (cand[d]) atomicAdd(cnt + d, 1);
}

// ---------- K2b: compact masked nodes + allocate adjacency regions ----------
extern "C" __global__ void __launch_bounds__(256)
k2b_alloc(const unsigned char* __restrict__ cand, const int* __restrict__ cnt,
          int* __restrict__ hdr, int* __restrict__ nodeoff,
          int* __restrict__ nlist, int N)
{
  int i = blockIdx.x * 256 + threadIdx.x;
  if (i >= N) return;
  int c = (cand[i] && cnt[i] > 0) ? cnt[i] : 0;
  if (c > 0) {
    int pos = atomicAdd(hdr + 4, 1);
    nlist[pos] = i;
    nodeoff[i] = atomicAdd(hdr + 5, c);
  } else {
    nodeoff[i] = -1;
  }
}

// ---------- K1b: fill adjacency lists of masked nodes ----------
extern "C" __global__ void __launch_bounds__(256)
k1_fill(const int* __restrict__ ei, const int* __restrict__ nodeoff,
        int* __restrict__ fillcnt, int* __restrict__ adj, int E,
        const int* __restrict__ hdr)
{
  int e = blockIdx.x * 256 + threadIdx.x;
  if (e >= E) return;
  int is64 = hdr[2];
  int s = ldei(ei, e, is64);
  int d = ldei(ei, (long)E + e, is64);
  int os = nodeoff[s];
  int od = nodeoff[d];
  if (os >= 0) { int p = atomicAdd(fillcnt + s, 1); adj[os + p] = d; }
  if (od >= 0) { int p = atomicAdd(fillcnt + d, 1); adj[od + p] = s; }
}

// ---------- K3: gather + MLP, persistent grid, 1 wave per node ----------
extern "C" __global__ void __launch_bounds__(64)
k3_mlp(const void* __restrict__ featv, const int* __restrict__ cnt,
       const int* __restrict__ nodeoff, const int* __restrict__ nlist,
       const int* __restrict__ adj, const float* __restrict__ wf,
       const int* __restrict__ hdr, float* __restrict__ out)
{
  const int t = threadIdx.x;             // 0..63 = feature lane
  const int dt = hdr[0];
  const int nmask = hdr[4];
  __shared__ float ctx[128];
  __shared__ float h1[128];
  __shared__ float h2[64];
  __shared__ float gen[67];
  __shared__ float pp[32];
  __shared__ float prob;

  for (int b = blockIdx.x; b < nmask; b += gridDim.x) {
    int node = nlist[b];
    int off = nodeoff[node];
    int dg = cnt[node];

    // gather neighbor mean (coalesced 256B row loads, 4-way unrolled)
    float acc = 0.f;
    int j = 0;
    for (; j + 4 <= dg; j += 4) {
      int n0 = adj[off + j + 0];
      int n1 = adj[off + j + 1];
      int n2 = adj[off + j + 2];
      int n3 = adj[off + j + 3];
      float v0 = ldf(featv, (long)n0 * 64 + t, dt);
      float v1 = ldf(featv, (long)n1 * 64 + t, dt);
      float v2 = ldf(featv, (long)n2 * 64 + t, dt);
      float v3 = ldf(featv, (long)n3 * 64 + t, dt);
      acc += ((v0 + v1) + (v2 + v3));
    }
    for (; j < dg; ++j) {
      int nb = adj[off + j];
      acc += ldf(featv, (long)nb * 64 + t, dt);
    }
    ctx[t]      = ldf(featv, (long)node * 64 + t, dt);
    ctx[64 + t] = acc / (float)dg;       // dg > 0 guaranteed
    __syncthreads();                     // block == 1 wave: cheap & safe

    // L1: y_j = b1[j] + sum_k ctx[k]*W1[k*128+j], relu
    for (int rep = 0; rep < 2; ++rep) {
      int jj = t + rep * 64;
      float a = wf[O_b1 + jj];
      for (int k = 0; k < 128; ++k) a = fmaf(ctx[k], wf[O_W1 + k * 128 + jj], a);
      h1[jj] = fmaxf(a, 0.f);
    }
    __syncthreads();

    // L2
    {
      float a = wf[O_b2 + t];
      for (int k = 0; k < 128; ++k) a = fmaf(h1[k], wf[O_W2 + k * 64 + t], a);
      h2[t] = fmaxf(a, 0.f);
    }
    __syncthreads();

    // L3
    for (int jj = t; jj < 67; jj += 64) {
      float a = wf[O_b3 + jj];
      for (int k = 0; k < 64; ++k) a = fmaf(h2[k], wf[O_W3 + k * 67 + jj], a);
      gen[jj] = a;
    }
    __syncthreads();

    // L4: input gen[3..66]
    if (t < 32) {
      float a = wf[O_pb1 + t];
      for (int k = 0; k < 64; ++k) a = fmaf(gen[3 + k], wf[O_P1 + k * 32 + t], a);
      pp[t] = fmaxf(a, 0.f);
    }
    __syncthreads();

    // L5
    if (t == 0) {
      float z = wf[O_pb2];
      for (int k = 0; k < 32; ++k) z = fmaf(pp[k], wf[O_P2 + k], z);
      prob = 1.0f / (1.0f + expf(-z));
    }
    __syncthreads();

    for (int c = t; c < 68; c += 64) {
      float v = (c < 67) ? gen[c] : prob;
      out[(long)node * 68 + c] = v;
    }
    __syncthreads();
  }
}

extern "C" void kernel_launch(void* const* d_in, const int* in_sizes, int n_in,
                              void* d_out, int out_size, void* d_ws, size_t ws_size,
                              hipStream_t stream) {
  // ---- identify tensors by element count (fallback: documented order) ----
  int iF = 0, iO = 1, iE = 2;
  int iW1 = 3, ib1 = 4, iW2 = 5, ib2 = 6, iW3 = 7, ib3 = 8;
  int iP1 = 9, ipb1 = 10, iP2 = 11, ipb2 = 12;
  {
    int bigs[4]; int nb = 0;
    for (int i = 0; i < n_in && nb < 4; ++i)
      if (in_sizes[i] > 100000) bigs[nb++] = i;
    if (nb == 3) {
      int a = bigs[0], b = bigs[1], c = bigs[2];
      int mx = a, mn = a;
      if (in_sizes[b] > in_sizes[mx]) mx = b;
      if (in_sizes[c] > in_sizes[mx]) mx = c;
      if (in_sizes[b] < in_sizes[mn]) mn = b;
      if (in_sizes[c] < in_sizes[mn]) mn = c;
      iF = mx; iO = mn; iE = a + b + c - mx - mn;
      int t32[2]; int n32 = 0;
      int jW1=-1, jb1=-1, jW2=-1, jb2=-1, jW3=-1, jb3=-1, jP1=-1, jpb2=-1;
      for (int i = 0; i < n_in; ++i) {
        if (i == iF || i == iO || i == iE) continue;
        switch (in_sizes[i]) {
          case 16384: jW1 = i; break;
          case 128:   jb1 = i; break;
          case 8192:  jW2 = i; break;
          case 64:    jb2 = i; break;
          case 4288:  jW3 = i; break;
          case 67:    jb3 = i; break;
          case 2048:  jP1 = i; break;
          case 1:     jpb2 = i; break;
          case 32:    if (n32 < 2) t32[n32++] = i; break;
          default: break;
        }
      }
      if (jW1 >= 0 && jb1 >= 0 && jW2 >= 0 && jb2 >= 0 && jW3 >= 0 &&
          jb3 >= 0 && jP1 >= 0 && jpb2 >= 0 && n32 == 2) {
        iW1 = jW1; ib1 = jb1; iW2 = jW2; ib2 = jb2; iW3 = jW3; ib3 = jb3;
        iP1 = jP1; ipb2 = jpb2;
        if (t32[1] == t32[0] + 1) { ipb1 = t32[0]; iP2 = t32[1]; }
        else                      { iP2 = t32[0]; ipb1 = t32[1]; }
      }
    }
  }
  int N = (out_size % 68 == 0) ? (out_size / 68) : (in_sizes[iF] / 64);
  const int E = in_sizes[iE] / 2;
  const void* feat = d_in[iF];
  const void* ops  = d_in[iO];
  const int* ei    = (const int*)d_in[iE];

  // workspace: hdr | wf | cand | cnt | nodeoff | fillcnt | nlist | adj(2E)
  char* ws = (char*)d_ws;
  int* hdr = (int*)ws;
  size_t off = 256;
  float* wf = (float*)(ws + off);
  off += ((size_t)W_TOTAL * 4 + 255) & ~(size_t)255;
  unsigned char* cand = (unsigned char*)(ws + off);
  off += ((size_t)N + 255) & ~(size_t)255;
  int* cnt = (int*)(ws + off);
  off += ((size_t)N * 4 + 255) & ~(size_t)255;
  int* nodeoff = (int*)(ws + off);
  off += ((size_t)N * 4 + 255) & ~(size_t)255;
  int* fillcnt = (int*)(ws + off);
  off += ((size_t)N * 4 + 255) & ~(size_t)255;
  int* nlist = (int*)(ws + off);
  off += ((size_t)N * 4 + 255) & ~(size_t)255;
  int* adj = (int*)(ws + off);

  hipMemsetAsync(hdr, 0, 256, stream);
  hipMemsetAsync(cnt, 0, (size_t)N * 4, stream);
  hipMemsetAsync(fillcnt, 0, (size_t)N * 4, stream);
  hipMemsetAsync(d_out, 0, (size_t)out_size * 4, stream);

  kd_detect<<<1, 64, 0, stream>>>((const u32*)feat, hdr, 0);
  kd_detect<<<1, 64, 0, stream>>>((const u32*)d_in[iW1], hdr, 1);
  kd_detect<<<1, 64, 0, stream>>>((const u32*)ops, hdr, 3);
  ke_detect<<<1, 64, 0, stream>>>((const u32*)ei, hdr);

  kw_conv<<<(W_TOTAL + 255) / 256, 256, 0, stream>>>(
      d_in[iW1], d_in[ib1], d_in[iW2], d_in[ib2], d_in[iW3], d_in[ib3],
      d_in[iP1], d_in[ipb1], d_in[iP2], d_in[ipb2], hdr, wf);
  k2a_cand<<<(N + 255) / 256, 256, 0, stream>>>(ops, hdr, cand, N);
  k1a_cnt<<<(E + 255) / 256, 256, 0, stream>>>(ei, cand, cnt, E, hdr);
  k2b_alloc<<<(N + 255) / 256, 256, 0, stream>>>(cand, cnt, hdr, nodeoff, nlist, N);
  k1_fill<<<(E + 255) / 256, 256, 0, stream>>>(ei, nodeoff, fillcnt, adj, E, hdr);
  k3_mlp<<<4096, 64, 0, stream>>>(feat, cnt, nodeoff, nlist, adj, wf, hdr,
                                  (float*)d_out);
}

// Round 12
// 296.901 us; speedup vs baseline: 1.8357x; 1.1457x over previous
//
#include <hip/hip_runtime.h>
#include <hip/hip_bf16.h>
#include <hip/hip_fp16.h>
#include <math.h>

typedef unsigned int u32;
typedef unsigned short u16;

// f32 weight-blob offsets (in floats)
#define O_W1 0
#define O_b1 16384
#define O_W2 16512
#define O_b2 24704
#define O_W3 24768
#define O_b3 29056
#define O_P1 29123
#define O_pb1 31171
#define O_P2 31203
#define O_pb2 31235
#define W_TOTAL 31236

#define LDP 65   // LDS leading-dim pad (65*4B: 2-way bank alias = free)

// dt codes: 0 = f32, 1 = bf16, 2 = f16
__device__ __forceinline__ float ldf(const void* p, long i, int dt) {
  if (dt == 1) { u32 v = ((const u16*)p)[i]; return __uint_as_float(v << 16); }
  if (dt == 2) { __half h = ((const __half*)p)[i]; return __half2float(h); }
  return ((const float*)p)[i];
}
__device__ __forceinline__ int ldei(const int* p, long i, int is64) {
  return is64 ? p[2 * i] : p[i];
}

// hdr: [0]=dt_feat [1]=dt_w [2]=ei is64 [3]=dt_ops [4]=masked count [5]=adj total
// ---------- merged detectors: block 0=feat,1=W1,2=ops,3=ei ----------
extern "C" __global__ void kall_detect(const u32* __restrict__ feat,
                                       const u32* __restrict__ w1,
                                       const u32* __restrict__ ops,
                                       const u32* __restrict__ ei,
                                       int* __restrict__ hdr)
{
  int lane = threadIdx.x;                 // 64 threads/block
  int mode = blockIdx.x;
  if (mode == 3) {                        // int64 edge check
    unsigned long long m0 = __ballot(ei[lane] == 0u);
    unsigned long long m1 = __ballot(ei[64 + lane] == 0u);
    if (lane == 0) hdr[2] = (__popcll(m0) + __popcll(m1) >= 32) ? 1 : 0;
    return;
  }
  const u32* p = (mode == 0) ? feat : (mode == 1) ? w1 : ops;
  int slot = (mode == 0) ? 0 : (mode == 1) ? 1 : 3;
  u32 w0 = p[lane];
  u32 w1v = p[64 + lane];
  u16 h[4] = { (u16)(w0 & 0xffff), (u16)(w0 >> 16),
               (u16)(w1v & 0xffff), (u16)(w1v >> 16) };
  int cb = 0;
#pragma unroll
  for (int t = 0; t < 4; ++t) {
    int e8 = (h[t] >> 7) & 0xff;
    cb += (e8 >= 110 && e8 <= 140) ? 1 : 0;
  }
  int ch = 0;                              // f16 check on EVEN u16s only
#pragma unroll
  for (int t = 0; t < 4; t += 2) {
    int e5 = (h[t] >> 10) & 0x1f;
    ch += (e5 >= 5 && e5 <= 18) ? 1 : 0;
  }
  __shared__ int sb[64], sh[64];
  sb[lane] = cb; sh[lane] = ch;
  __syncthreads();
  if (lane == 0) {
    int CB = 0, CH = 0;
    for (int t = 0; t < 64; ++t) { CB += sb[t]; CH += sh[t]; }
    int dt;
    if (CB >= 200) dt = 1;
    else if (CH >= 100) dt = 2;
    else dt = 0;
    hdr[slot] = dt;
  }
}

// ---------- KW: weights -> f32 blob ----------
extern "C" __global__ void __launch_bounds__(256)
kw_conv(const void* __restrict__ W1, const void* __restrict__ b1,
        const void* __restrict__ W2, const void* __restrict__ b2,
        const void* __restrict__ W3, const void* __restrict__ b3,
        const void* __restrict__ P1, const void* __restrict__ pb1,
        const void* __restrict__ P2, const void* __restrict__ pb2,
        const int* __restrict__ hdr, float* __restrict__ wf)
{
  int i = blockIdx.x * 256 + threadIdx.x;
  if (i >= W_TOTAL) return;
  const void* s; int o;
  if      (i < O_b1)  { s = W1;  o = i; }
  else if (i < O_W2)  { s = b1;  o = i - O_b1; }
  else if (i < O_b2)  { s = W2;  o = i - O_W2; }
  else if (i < O_W3)  { s = b2;  o = i - O_b2; }
  else if (i < O_b3)  { s = W3;  o = i - O_W3; }
  else if (i < O_P1)  { s = b3;  o = i - O_b3; }
  else if (i < O_pb1) { s = P1;  o = i - O_P1; }
  else if (i < O_P2)  { s = pb1; o = i - O_pb1; }
  else if (i < O_pb2) { s = P2;  o = i - O_P2; }
  else                { s = pb2; o = i - O_pb2; }
  wf[i] = ldf(s, o, hdr[1]);
}

// ---------- K2a: candidate flags (p0 > 0.5), no atomics ----------
extern "C" __global__ void __launch_bounds__(256)
k2a_cand(const void* __restrict__ opsv, const int* __restrict__ hdr,
         unsigned char* __restrict__ cand, int N)
{
  int i = blockIdx.x * 256 + threadIdx.x;
  if (i >= N) return;
  int dt = hdr[3];
  float x0 = ldf(opsv, (long)i * 4 + 0, dt);
  float x1 = ldf(opsv, (long)i * 4 + 1, dt);
  float x2 = ldf(opsv, (long)i * 4 + 2, dt);
  float x3 = ldf(opsv, (long)i * 4 + 3, dt);
  float m = fmaxf(fmaxf(x0, x1), fmaxf(x2, x3));
  double e0 = exp((double)(x0 - m));
  double e1 = exp((double)(x1 - m));
  double e2 = exp((double)(x2 - m));
  double e3 = exp((double)(x3 - m));
  double p0 = e0 / (((e0 + e1) + e2) + e3);
  cand[i] = (p0 > 0.5) ? 1 : 0;
}

// ---------- K1a: count degrees ONLY for candidate endpoints ----------
extern "C" __global__ void __launch_bounds__(256)
k1a_cnt(const int* __restrict__ ei, const unsigned char* __restrict__ cand,
        int* __restrict__ cnt, int E, const int* __restrict__ hdr)
{
  int e = blockIdx.x * 256 + threadIdx.x;
  if (e >= E) return;
  int is64 = hdr[2];
  int s = ldei(ei, e, is64);
  int d = ldei(ei, (long)E + e, is64);
  if (cand[s]) atomicAdd(cnt + s, 1);
  if (cand[d]) atomicAdd(cnt + d, 1);
}

// ---------- K2b: compact masked nodes + allocate adjacency regions ----------
extern "C" __global__ void __launch_bounds__(256)
k2b_alloc(const unsigned char* __restrict__ cand, const int* __restrict__ cnt,
          int* __restrict__ hdr, int* __restrict__ nodeoff,
          int* __restrict__ nlist, int N)
{
  int i = blockIdx.x * 256 + threadIdx.x;
  if (i >= N) return;
  int c = (cand[i] && cnt[i] > 0) ? cnt[i] : 0;
  if (c > 0) {
    int pos = atomicAdd(hdr + 4, 1);
    nlist[pos] = i;
    nodeoff[i] = atomicAdd(hdr + 5, c);
  } else {
    nodeoff[i] = -1;
  }
}

// ---------- K1b: fill adjacency lists of masked nodes ----------
extern "C" __global__ void __launch_bounds__(256)
k1_fill(const int* __restrict__ ei, const int* __restrict__ nodeoff,
        int* __restrict__ fillcnt, int* __restrict__ adj, int E,
        const int* __restrict__ hdr)
{
  int e = blockIdx.x * 256 + threadIdx.x;
  if (e >= E) return;
  int is64 = hdr[2];
  int s = ldei(ei, e, is64);
  int d = ldei(ei, (long)E + e, is64);
  int os = nodeoff[s];
  int od = nodeoff[d];
  if (os >= 0) { int p = atomicAdd(fillcnt + s, 1); adj[os + p] = d; }
  if (od >= 0) { int p = atomicAdd(fillcnt + d, 1); adj[od + p] = s; }
}

// ---------- K3a: neighbor mean, wave per masked node, persistent ----------
// writes mean into out[node*68 + 0..63] (masked rows are overwritten by k3b)
extern "C" __global__ void __launch_bounds__(256)
k3a_gather(const void* __restrict__ featv, const int* __restrict__ cnt,
           const int* __restrict__ nodeoff, const int* __restrict__ nlist,
           const int* __restrict__ adj, const int* __restrict__ hdr,
           float* __restrict__ out)
{
  const int lane = threadIdx.x & 63;
  const int q = __builtin_amdgcn_readfirstlane(threadIdx.x >> 6);
  const int dt = hdr[0];
  const int nmask = hdr[4];
  for (long b = (long)blockIdx.x * 4 + q; b < nmask; b += (long)gridDim.x * 4) {
    int node = nlist[b];
    int off = nodeoff[node];
    int dg = cnt[node];
    float acc = 0.f;
    int j = 0;
    for (; j + 4 <= dg; j += 4) {
      int n0 = adj[off + j + 0];
      int n1 = adj[off + j + 1];
      int n2 = adj[off + j + 2];
      int n3 = adj[off + j + 3];
      float v0 = ldf(featv, (long)n0 * 64 + lane, dt);
      float v1 = ldf(featv, (long)n1 * 64 + lane, dt);
      float v2 = ldf(featv, (long)n2 * 64 + lane, dt);
      float v3 = ldf(featv, (long)n3 * 64 + lane, dt);
      acc += ((v0 + v1) + (v2 + v3));
    }
    for (; j < dg; ++j)
      acc += ldf(featv, (long)adj[off + j] * 64 + lane, dt);
    out[(long)node * 68 + lane] = acc / (float)dg;
  }
}

// ---------- K3b: batched MLP, 64 nodes/block, lane = node ----------
extern "C" __global__ void __launch_bounds__(256)
k3b_mlp(const void* __restrict__ featv, const int* __restrict__ nlist,
        const float* __restrict__ wf, const int* __restrict__ hdr,
        float* __restrict__ out)
{
  __shared__ float A[128 * LDP];
  __shared__ float B[128 * LDP];
  const int tid = threadIdx.x;
  const int lane = tid & 63;
  const int q = __builtin_amdgcn_readfirstlane(tid >> 6);
  const int dt = hdr[0];
  const int nmask = hdr[4];
  const int base = blockIdx.x * 64;
  if (nmask == 0 || base >= nmask) return;

  // stage ctx: rows 0..63 node features, rows 64..127 neighbor mean
  for (int i = 0; i < 16; ++i) {
    int g = i * 256 + tid;
    int nloc = g >> 6, f = g & 63;
    int idx = base + nloc;
    int cidx = (idx < nmask) ? idx : (nmask - 1);
    int node = nlist[cidx];
    A[f * LDP + nloc] = ldf(featv, (long)node * 64 + f, dt);
    A[(64 + f) * LDP + nloc] = out[(long)node * 68 + f];   // mean from k3a
  }
  __syncthreads();

  // L1: 128 -> 128, relu. wave q: j in [q*32, q*32+32)
  for (int jg = 0; jg < 32; jg += 4) {
    int j = q * 32 + jg;
    float a0 = wf[O_b1 + j + 0];
    float a1 = wf[O_b1 + j + 1];
    float a2 = wf[O_b1 + j + 2];
    float a3 = wf[O_b1 + j + 3];
    for (int k = 0; k < 128; ++k) {
      float x = A[k * LDP + lane];
      const float* w = wf + O_W1 + k * 128 + j;
      a0 = fmaf(x, w[0], a0);
      a1 = fmaf(x, w[1], a1);
      a2 = fmaf(x, w[2], a2);
      a3 = fmaf(x, w[3], a3);
    }
    B[(j + 0) * LDP + lane] = fmaxf(a0, 0.f);
    B[(j + 1) * LDP + lane] = fmaxf(a1, 0.f);
    B[(j + 2) * LDP + lane] = fmaxf(a2, 0.f);
    B[(j + 3) * LDP + lane] = fmaxf(a3, 0.f);
  }
  __syncthreads();

  // L2: 128 -> 64, relu. wave q: j in [q*16, q*16+16). writes A rows 0..63
  for (int jg = 0; jg < 16; jg += 4) {
    int j = q * 16 + jg;
    float a0 = wf[O_b2 + j + 0];
    float a1 = wf[O_b2 + j + 1];
    float a2 = wf[O_b2 + j + 2];
    float a3 = wf[O_b2 + j + 3];
    for (int k = 0; k < 128; ++k) {
      float x = B[k * LDP + lane];
      const float* w = wf + O_W2 + k * 64 + j;
      a0 = fmaf(x, w[0], a0);
      a1 = fmaf(x, w[1], a1);
      a2 = fmaf(x, w[2], a2);
      a3 = fmaf(x, w[3], a3);
    }
    A[(j + 0) * LDP + lane] = fmaxf(a0, 0.f);
    A[(j + 1) * LDP + lane] = fmaxf(a1, 0.f);
    A[(j + 2) * LDP + lane] = fmaxf(a2, 0.f);
    A[(j + 3) * LDP + lane] = fmaxf(a3, 0.f);
  }
  __syncthreads();

  // L3: 64 -> 67 (no relu). wave q: j in [q*17, min(q*17+17,67)). writes B
  {
    int j0 = q * 17;
    int jend = min(j0 + 17, 67);
    for (int j = j0; j < jend; ++j) {
      float a0 = 0.f, a1 = 0.f, a2 = 0.f, a3 = 0.f;
      for (int k = 0; k < 64; k += 4) {
        a0 = fmaf(A[(k + 0) * LDP + lane], wf[O_W3 + (k + 0) * 67 + j], a0);
        a1 = fmaf(A[(k + 1) * LDP + lane], wf[O_W3 + (k + 1) * 67 + j], a1);
        a2 = fmaf(A[(k + 2) * LDP + lane], wf[O_W3 + (k + 2) * 67 + j], a2);
        a3 = fmaf(A[(k + 3) * LDP + lane], wf[O_W3 + (k + 3) * 67 + j], a3);
      }
      B[j * LDP + lane] = wf[O_b3 + j] + ((a0 + a1) + (a2 + a3));
    }
  }
  __syncthreads();

  // L4: gen[3..66] -> 32, relu. wave q: j in [q*8, q*8+8). writes A rows 0..31
  for (int jg = 0; jg < 8; jg += 4) {
    int j = q * 8 + jg;
    float a0 = wf[O_pb1 + j + 0];
    float a1 = wf[O_pb1 + j + 1];
    float a2 = wf[O_pb1 + j + 2];
    float a3 = wf[O_pb1 + j + 3];
    for (int k = 0; k < 64; ++k) {
      float x = B[(3 + k) * LDP + lane];
      const float* w = wf + O_P1 + k * 32 + j;
      a0 = fmaf(x, w[0], a0);
      a1 = fmaf(x, w[1], a1);
      a2 = fmaf(x, w[2], a2);
      a3 = fmaf(x, w[3], a3);
    }
    A[(j + 0) * LDP + lane] = fmaxf(a0, 0.f);
    A[(j + 1) * LDP + lane] = fmaxf(a1, 0.f);
    A[(j + 2) * LDP + lane] = fmaxf(a2, 0.f);
    A[(j + 3) * LDP + lane] = fmaxf(a3, 0.f);
  }
  __syncthreads();

  // L5: 32 -> sigmoid prob. wave 0 only. writes B row 67
  if (q == 0) {
    float a0 = 0.f, a1 = 0.f, a2 = 0.f, a3 = 0.f;
    for (int k = 0; k < 32; k += 4) {
      a0 = fmaf(A[(k + 0) * LDP + lane], wf[O_P2 + k + 0], a0);
      a1 = fmaf(A[(k + 1) * LDP + lane], wf[O_P2 + k + 1], a1);
      a2 = fmaf(A[(k + 2) * LDP + lane], wf[O_P2 + k + 2], a2);
      a3 = fmaf(A[(k + 3) * LDP + lane], wf[O_P2 + k + 3], a3);
    }
    float z = wf[O_pb2] + ((a0 + a1) + (a2 + a3));
    B[67 * LDP + lane] = 1.0f / (1.0f + expf(-z));
  }
  __syncthreads();

  // store: channels q*17 .. q*17+16 (covers 0..67)
  if (base + lane < nmask) {
    int node = nlist[base + lane];
    float* orow = out + (long)node * 68;
#pragma unroll
    for (int tt = 0; tt < 17; ++tt) {
      int c = q * 17 + tt;
      orow[c] = B[c * LDP + lane];
    }
  }
}

extern "C" void kernel_launch(void* const* d_in, const int* in_sizes, int n_in,
                              void* d_out, int out_size, void* d_ws, size_t ws_size,
                              hipStream_t stream) {
  // ---- identify tensors by element count (fallback: documented order) ----
  int iF = 0, iO = 1, iE = 2;
  int iW1 = 3, ib1 = 4, iW2 = 5, ib2 = 6, iW3 = 7, ib3 = 8;
  int iP1 = 9, ipb1 = 10, iP2 = 11, ipb2 = 12;
  {
    int bigs[4]; int nb = 0;
    for (int i = 0; i < n_in && nb < 4; ++i)
      if (in_sizes[i] > 100000) bigs[nb++] = i;
    if (nb == 3) {
      int a = bigs[0], b = bigs[1], c = bigs[2];
      int mx = a, mn = a;
      if (in_sizes[b] > in_sizes[mx]) mx = b;
      if (in_sizes[c] > in_sizes[mx]) mx = c;
      if (in_sizes[b] < in_sizes[mn]) mn = b;
      if (in_sizes[c] < in_sizes[mn]) mn = c;
      iF = mx; iO = mn; iE = a + b + c - mx - mn;
      int t32[2]; int n32 = 0;
      int jW1=-1, jb1=-1, jW2=-1, jb2=-1, jW3=-1, jb3=-1, jP1=-1, jpb2=-1;
      for (int i = 0; i < n_in; ++i) {
        if (i == iF || i == iO || i == iE) continue;
        switch (in_sizes[i]) {
          case 16384: jW1 = i; break;
          case 128:   jb1 = i; break;
          case 8192:  jW2 = i; break;
          case 64:    jb2 = i; break;
          case 4288:  jW3 = i; break;
          case 67:    jb3 = i; break;
          case 2048:  jP1 = i; break;
          case 1:     jpb2 = i; break;
          case 32:    if (n32 < 2) t32[n32++] = i; break;
          default: break;
        }
      }
      if (jW1 >= 0 && jb1 >= 0 && jW2 >= 0 && jb2 >= 0 && jW3 >= 0 &&
          jb3 >= 0 && jP1 >= 0 && jpb2 >= 0 && n32 == 2) {
        iW1 = jW1; ib1 = jb1; iW2 = jW2; ib2 = jb2; iW3 = jW3; ib3 = jb3;
        iP1 = jP1; ipb2 = jpb2;
        if (t32[1] == t32[0] + 1) { ipb1 = t32[0]; iP2 = t32[1]; }
        else                      { iP2 = t32[0]; ipb1 = t32[1]; }
      }
    }
  }
  int N = (out_size % 68 == 0) ? (out_size / 68) : (in_sizes[iF] / 64);
  const int E = in_sizes[iE] / 2;
  const void* feat = d_in[iF];
  const void* ops  = d_in[iO];
  const int* ei    = (const int*)d_in[iE];

  // workspace: hdr | wf | cand | cnt | nodeoff | fillcnt | nlist | adj(2E)
  char* ws = (char*)d_ws;
  int* hdr = (int*)ws;
  size_t off = 256;
  float* wf = (float*)(ws + off);
  off += ((size_t)W_TOTAL * 4 + 255) & ~(size_t)255;
  unsigned char* cand = (unsigned char*)(ws + off);
  off += ((size_t)N + 255) & ~(size_t)255;
  int* cnt = (int*)(ws + off);
  off += ((size_t)N * 4 + 255) & ~(size_t)255;
  int* nodeoff = (int*)(ws + off);
  off += ((size_t)N * 4 + 255) & ~(size_t)255;
  int* fillcnt = (int*)(ws + off);
  off += ((size_t)N * 4 + 255) & ~(size_t)255;
  int* nlist = (int*)(ws + off);
  off += ((size_t)N * 4 + 255) & ~(size_t)255;
  int* adj = (int*)(ws + off);

  hipMemsetAsync(hdr, 0, 256, stream);
  hipMemsetAsync(cnt, 0, (size_t)N * 4, stream);
  hipMemsetAsync(fillcnt, 0, (size_t)N * 4, stream);
  hipMemsetAsync(d_out, 0, (size_t)out_size * 4, stream);

  kall_detect<<<4, 64, 0, stream>>>((const u32*)feat, (const u32*)d_in[iW1],
                                    (const u32*)ops, (const u32*)ei, hdr);

  kw_conv<<<(W_TOTAL + 255) / 256, 256, 0, stream>>>(
      d_in[iW1], d_in[ib1], d_in[iW2], d_in[ib2], d_in[iW3], d_in[ib3],
      d_in[iP1], d_in[ipb1], d_in[iP2], d_in[ipb2], hdr, wf);
  k2a_cand<<<(N + 255) / 256, 256, 0, stream>>>(ops, hdr, cand, N);
  k1a_cnt<<<(E + 255) / 256, 256, 0, stream>>>(ei, cand, cnt, E, hdr);
  k2b_alloc<<<(N + 255) / 256, 256, 0, stream>>>(cand, cnt, hdr, nodeoff, nlist, N);
  k1_fill<<<(E + 255) / 256, 256, 0, stream>>>(ei, nodeoff, fillcnt, adj, E, hdr);
  k3a_gather<<<2048, 256, 0, stream>>>(feat, cnt, nodeoff, nlist, adj, hdr,
                                       (float*)d_out);
  k3b_mlp<<<(N + 63) / 64, 256, 0, stream>>>(feat, nlist, wf, hdr,
                                             (float*)d_out);
}